// Round 3
// baseline (844.489 us; speedup 1.0000x reference)
//
#include <hip/hip_runtime.h>
#include <hip/hip_bf16.h>
#include <cstdint>
#include <cstddef>

using bf16 = __hip_bfloat16;
typedef __attribute__((ext_vector_type(8))) short bf16x8;
typedef __attribute__((ext_vector_type(4))) float floatx4;

#define GLOBAL_AS __attribute__((address_space(1)))
#define LDS_AS    __attribute__((address_space(3)))

__device__ __forceinline__ void async_copy16(void* lds, const void* g) {
    __builtin_amdgcn_global_load_lds((GLOBAL_AS void*)(g), (LDS_AS void*)(lds), 16, 0, 0);
}

__device__ __forceinline__ floatx4 mfma_bf16(bf16x8 a, bf16x8 b, floatx4 c) {
    return __builtin_amdgcn_mfma_f32_16x16x32_bf16(a, b, c, 0, 0, 0);
}

// fp32 -> bf16 elementwise, 4 elements/thread. n must be a multiple of 4.
__global__ void cvt_f32_bf16(const float* __restrict__ src, bf16* __restrict__ dst, int n) {
    int i = (blockIdx.x * blockDim.x + threadIdx.x) * 4;
    if (i < n) {
        float4 v = *(const float4*)(src + i);
        __align__(8) bf16 t[4];
        t[0] = __float2bfloat16(v.x);
        t[1] = __float2bfloat16(v.y);
        t[2] = __float2bfloat16(v.z);
        t[3] = __float2bfloat16(v.w);
        *(short4*)(dst + i) = *(const short4*)t;
    }
}

// C[m,n] = (sum_k A[m,k] * W[n,k] + bias[n]) * cscale.   (bias is fp32)
// OUTF==0: C bf16 [M][N] row-major; OUTF==1: C fp32 [M][N] row-major.
// cscale lets the attention 1/sqrt(d) factor be folded into the Q
// projection for free (saves 16 v_mul per tile-unit per lane in attn).
template <int OUTF>
__global__ __launch_bounds__(256, 3) void gemm_bt_bias(
    const bf16* __restrict__ A, const bf16* __restrict__ W,
    const float* __restrict__ bias, void* __restrict__ Cv,
    int M, int N, int K, float cscale)
{
    __shared__ __align__(16) bf16 As[128 * 32];
    __shared__ __align__(16) bf16 Ws[128 * 32];

    const int tid  = threadIdx.x;
    const int lane = tid & 63;
    const int wave = tid >> 6;
    const int quad = lane >> 4;
    const int l16  = lane & 15;
    const int wm = (wave >> 1) * 64;
    const int wn = (wave & 1) * 64;

    const int bm = blockIdx.x;
    const int bn = blockIdx.y;

    floatx4 acc[4][4];
#pragma unroll
    for (int i = 0; i < 4; ++i)
#pragma unroll
        for (int j = 0; j < 4; ++j) acc[i][j] = (floatx4){0.f, 0.f, 0.f, 0.f};

    const int srow = tid >> 2;
    const int scol = (tid & 3) * 8;
    const bf16* gA = A + (size_t)(bm * 128 + srow) * K + scol;
    const bf16* gW = W + (size_t)(bn * 128 + srow) * K + scol;
    bf16* lA0 = As + tid * 8;
    bf16* lA1 = As + 2048 + tid * 8;
    bf16* lW0 = Ws + tid * 8;
    bf16* lW1 = Ws + 2048 + tid * 8;
    const size_t skip = (size_t)64 * K;

    const int kt_n = K >> 5;
    for (int kt = 0; kt < kt_n; ++kt) {
        __syncthreads();
        const bf16* ga = gA + kt * 32;
        const bf16* gw = gW + kt * 32;
        async_copy16(lA0, ga);
        async_copy16(lA1, ga + skip);
        async_copy16(lW0, gw);
        async_copy16(lW1, gw + skip);
        __syncthreads();

        bf16x8 af[4], bfr[4];
#pragma unroll
        for (int mi = 0; mi < 4; ++mi)
            af[mi] = *(const bf16x8*)(As + (wm + mi * 16 + l16) * 32 + quad * 8);
#pragma unroll
        for (int ni = 0; ni < 4; ++ni)
            bfr[ni] = *(const bf16x8*)(Ws + (wn + ni * 16 + l16) * 32 + quad * 8);
#pragma unroll
        for (int mi = 0; mi < 4; ++mi)
#pragma unroll
            for (int ni = 0; ni < 4; ++ni)
                acc[mi][ni] = mfma_bf16(af[mi], bfr[ni], acc[mi][ni]);
    }

#pragma unroll
    for (int mi = 0; mi < 4; ++mi) {
        const int row0 = bm * 128 + wm + mi * 16 + quad * 4;
#pragma unroll
        for (int ni = 0; ni < 4; ++ni) {
            const int col = bn * 128 + wn + ni * 16 + l16;
            const float bv = bias[col];
            if (OUTF) {
                float* C = (float*)Cv;
#pragma unroll
                for (int r = 0; r < 4; ++r)
                    C[(size_t)(row0 + r) * N + col] = (acc[mi][ni][r] + bv) * cscale;
            } else {
                bf16* C = (bf16*)Cv;
#pragma unroll
                for (int r = 0; r < 4; ++r)
                    C[(size_t)(row0 + r) * N + col] = __float2bfloat16((acc[mi][ni][r] + bv) * cscale);
            }
        }
    }
}

// Fused K+V projection. Logical N=2048: bn<8 -> K rows (k_buf row-major
// [M][1024] bf16); bn>=8 -> V rows (vt [B][1024][T] transposed bf16 store).
__global__ __launch_bounds__(256, 3) void gemm_kv(
    const bf16* __restrict__ A,
    const bf16* __restrict__ Wk, const bf16* __restrict__ Wv,
    const float* __restrict__ bk, const float* __restrict__ bv,
    bf16* __restrict__ kout, bf16* __restrict__ vt,
    int M, int K)
{
    __shared__ __align__(16) bf16 As[128 * 32];
    __shared__ __align__(16) bf16 Ws[128 * 32];

    const int tid  = threadIdx.x;
    const int lane = tid & 63;
    const int wave = tid >> 6;
    const int quad = lane >> 4;
    const int l16  = lane & 15;
    const int wm = (wave >> 1) * 64;
    const int wn = (wave & 1) * 64;

    const int bm = blockIdx.x;
    const int bn = blockIdx.y;
    const bool isK = (bn < 8);
    const int nb = isK ? bn : (bn - 8);
    const bf16* Wsel  = isK ? Wk : Wv;
    const float* bsel = isK ? bk : bv;

    floatx4 acc[4][4];
#pragma unroll
    for (int i = 0; i < 4; ++i)
#pragma unroll
        for (int j = 0; j < 4; ++j) acc[i][j] = (floatx4){0.f, 0.f, 0.f, 0.f};

    const int srow = tid >> 2;
    const int scol = (tid & 3) * 8;
    const bf16* gA = A    + (size_t)(bm * 128 + srow) * K + scol;
    const bf16* gW = Wsel + (size_t)(nb * 128 + srow) * K + scol;
    bf16* lA0 = As + tid * 8;
    bf16* lA1 = As + 2048 + tid * 8;
    bf16* lW0 = Ws + tid * 8;
    bf16* lW1 = Ws + 2048 + tid * 8;
    const size_t skip = (size_t)64 * K;

    const int kt_n = K >> 5;
    for (int kt = 0; kt < kt_n; ++kt) {
        __syncthreads();
        const bf16* ga = gA + kt * 32;
        const bf16* gw = gW + kt * 32;
        async_copy16(lA0, ga);
        async_copy16(lA1, ga + skip);
        async_copy16(lW0, gw);
        async_copy16(lW1, gw + skip);
        __syncthreads();

        bf16x8 af[4], bfr[4];
#pragma unroll
        for (int mi = 0; mi < 4; ++mi)
            af[mi] = *(const bf16x8*)(As + (wm + mi * 16 + l16) * 32 + quad * 8);
#pragma unroll
        for (int ni = 0; ni < 4; ++ni)
            bfr[ni] = *(const bf16x8*)(Ws + (wn + ni * 16 + l16) * 32 + quad * 8);
#pragma unroll
        for (int mi = 0; mi < 4; ++mi)
#pragma unroll
            for (int ni = 0; ni < 4; ++ni)
                acc[mi][ni] = mfma_bf16(af[mi], bfr[ni], acc[mi][ni]);
    }

#pragma unroll
    for (int mi = 0; mi < 4; ++mi) {
        const int row0 = bm * 128 + wm + mi * 16 + quad * 4;
#pragma unroll
        for (int ni = 0; ni < 4; ++ni) {
            const int col = nb * 128 + wn + ni * 16 + l16;
            const float bvv = bsel[col];
            if (isK) {
#pragma unroll
                for (int r = 0; r < 4; ++r)
                    kout[(size_t)(row0 + r) * 1024 + col] = __float2bfloat16(acc[mi][ni][r] + bvv);
            } else {
                __align__(8) bf16 tmp[4];
#pragma unroll
                for (int r = 0; r < 4; ++r) tmp[r] = __float2bfloat16(acc[mi][ni][r] + bvv);
                const int b  = row0 >> 11;      // T = 2048
                const int t0 = row0 & 2047;
                bf16* dst = vt + ((size_t)(b * 1024 + col)) * 2048 + t0;
                *(short4*)dst = *(const short4*)tmp;
            }
        }
    }
}

// Flash attention, causal, balanced q-tile pairing.
// Block (qi, bh) handles q-tiles qtB=31-qi (large) and qtA=qi (small).
// v7: softmax VALU diet.
//  - scale folded into Q projection (gemm epilogue) -> no per-element mul.
//  - T13 defer-max (THR=8): skip alpha-exp + 32 oacc rescale muls when
//    __all(mx <= m_run + 8) (wave-uniform branch). P bounded by e^8,
//    bf16-safe; l/O accumulate in fp32.
//  - T5 setprio(1) around both MFMA clusters (waves here run phases
//    unsynced -> scheduler has roles to arbitrate).
//  - (from v6) Q in registers; K/V double-buffered global_load_lds DMA,
//    prefetch at top of iteration; both-sides XOR swizzle.
__global__ __launch_bounds__(256, 2) void attn_fwd(
    const bf16* __restrict__ qb, const bf16* __restrict__ kb,
    const bf16* __restrict__ vtb, bf16* __restrict__ ob)
{
    constexpr int T  = 2048;
    constexpr int DQ = 4096;
    constexpr int DK = 1024;

    __shared__ __align__(16) bf16 Ks[2][64 * 128];   // [buf][row 0..63][col granule], linear
    __shared__ __align__(16) bf16 Vs[2][128 * 64];   // [buf][d 0..127][s granule], linear
    __shared__ __align__(16) bf16 Ps[4][16][72];     // per-wave P tile

    const int tid  = threadIdx.x;
    const int lane = tid & 63;
    const int wave = tid >> 6;
    const int quad = lane >> 4;
    const int l16  = lane & 15;
    const int swz  = l16 & 7;

    const int qi = blockIdx.x;    // 0..15
    const int bh = blockIdx.y;
    const int b  = bh >> 5;
    const int h  = bh & 31;
    const int g  = h >> 2;        // GROUP = 4
    const int qtB = 31 - qi;      // large tile
    const int qtA = qi;           // small tile
    const int q0B = qtB * 64;
    const int q0A = qtA * 64;
    const int qw = wave * 16;

    const bf16* Qg = qb  + (size_t)b * T * DQ + (size_t)h * 128;
    const bf16* Kg = kb  + (size_t)b * T * DK + (size_t)g * 128;
    const bf16* Vg = vtb + ((size_t)b * DK + g * 128) * T;
    bf16*       Og = ob  + (size_t)b * T * DQ + (size_t)h * 128;

    // ---- Q fragments -> registers (16 q-rows per wave per tile) ----
    bf16x8 qf[2][4];
    {
        const size_t rB = (size_t)(q0B + qw + l16) * DQ;
        const size_t rA = (size_t)(q0A + qw + l16) * DQ;
#pragma unroll
        for (int kk = 0; kk < 4; ++kk) {
            qf[0][kk] = *(const bf16x8*)(Qg + rB + kk * 32 + quad * 8);
            qf[1][kk] = *(const bf16x8*)(Qg + rA + kk * 32 + quad * 8);
        }
    }

    // staging geometry (per-thread, 16B granules)
    const int krow_l = tid >> 4;   // K tile: row = i*16 + krow_l, col16 = tid&15
    const int kc16   = tid & 15;
    const int vrow_l = tid >> 3;   // V tile: row = i*32 + vrow_l, col16 = tid&7
    const int vc16   = tid & 7;

    // Stage tile st_ into buffer bi_: 8 global_load_lds per thread.
    // LDS dest is LINEAR (base + lane*16B per wave); global source column
    // is pre-swizzled with (row & 7).
    auto STAGE = [&](int st_, int bi_) {
        const int s0_ = st_ * 64;
        bf16* kbp = &Ks[bi_][0];
        bf16* vbp = &Vs[bi_][0];
#pragma unroll
        for (int i = 0; i < 4; ++i) {
            const int r = i * 16 + krow_l;
            async_copy16(kbp + (i * 256 + tid) * 8,
                         Kg + (size_t)(s0_ + r) * DK + ((kc16 ^ (r & 7)) * 8));
        }
#pragma unroll
        for (int i = 0; i < 4; ++i) {
            const int r = i * 32 + vrow_l;
            async_copy16(vbp + (i * 256 + tid) * 8,
                         Vg + (size_t)r * T + s0_ + ((vc16 ^ (r & 7)) * 8));
        }
    };

    floatx4 oacc[2][8];
#pragma unroll
    for (int t = 0; t < 2; ++t)
#pragma unroll
        for (int i = 0; i < 8; ++i) oacc[t][i] = (floatx4){0.f, 0.f, 0.f, 0.f};
    float m_run[2][4], l_run[2][4];
#pragma unroll
    for (int t = 0; t < 2; ++t)
#pragma unroll
        for (int r = 0; r < 4; ++r) { m_run[t][r] = -1e30f; l_run[t][r] = 0.f; }

    STAGE(0, 0);
    __syncthreads();   // drains vmcnt: tile 0 resident in LDS for all waves

    for (int st = 0; st <= qtB; ++st) {
        const int bi = st & 1;
        const int s0 = st * 64;

        if (st < qtB) STAGE(st + 1, bi ^ 1);   // prefetch next tile into other buffer

        const bf16* Kb = &Ks[bi][0];
        const bf16* Vb = &Vs[bi][0];

        const int ntile = (st <= qtA) ? 2 : 1;
#pragma unroll
        for (int t = 0; t < 2; ++t) {
            if (t >= ntile) break;
            const int q0t  = t ? q0A : q0B;
            const int qt_t = t ? qtA : qtB;

            // S[16q][64s] for this tile (Q pre-scaled by 1/sqrt(d))
            floatx4 sacc[4];
#pragma unroll
            for (int i = 0; i < 4; ++i) sacc[i] = (floatx4){0.f, 0.f, 0.f, 0.f};
            __builtin_amdgcn_s_setprio(1);
#pragma unroll
            for (int kk = 0; kk < 4; ++kk) {
                const int koff = ((kk * 4 + quad) ^ swz) * 8;
#pragma unroll
                for (int ni = 0; ni < 4; ++ni) {
                    bf16x8 bk8 = *(const bf16x8*)(Kb + (ni * 16 + l16) * 128 + koff);
                    sacc[ni] = mfma_bf16(qf[t][kk], bk8, sacc[ni]);
                }
            }
            __builtin_amdgcn_s_setprio(0);

            const bool diag = (st == qt_t);
#pragma unroll
            for (int r = 0; r < 4; ++r) {
                const int qg = q0t + qw + quad * 4 + r;   // C/D row = quad*4+reg
                float sv[4];
#pragma unroll
                for (int ni = 0; ni < 4; ++ni) {
                    float x = sacc[ni][r];
                    if (diag && (s0 + ni * 16 + l16) > qg) x = -1e30f;
                    sv[ni] = x;
                }
                float mx = fmaxf(fmaxf(sv[0], sv[1]), fmaxf(sv[2], sv[3]));
                mx = fmaxf(mx, __shfl_xor(mx, 1, 64));
                mx = fmaxf(mx, __shfl_xor(mx, 2, 64));
                mx = fmaxf(mx, __shfl_xor(mx, 4, 64));
                mx = fmaxf(mx, __shfl_xor(mx, 8, 64));
                const float mold = m_run[t][r];
                float ssum = 0.f;
                if (__all(mx <= mold + 8.0f)) {
                    // defer-max: keep old running max; P bounded by e^8.
#pragma unroll
                    for (int ni = 0; ni < 4; ++ni) {
                        float p = __expf(sv[ni] - mold);
                        ssum += p;
                        Ps[wave][quad * 4 + r][ni * 16 + l16] = __float2bfloat16(p);
                    }
                    ssum += __shfl_xor(ssum, 1, 64);
                    ssum += __shfl_xor(ssum, 2, 64);
                    ssum += __shfl_xor(ssum, 4, 64);
                    ssum += __shfl_xor(ssum, 8, 64);
                    l_run[t][r] += ssum;
                } else {
                    const float mnew  = fmaxf(mold, mx);
                    const float alpha = __expf(mold - mnew);
#pragma unroll
                    for (int ni = 0; ni < 4; ++ni) {
                        float p = __expf(sv[ni] - mnew);
                        ssum += p;
                        Ps[wave][quad * 4 + r][ni * 16 + l16] = __float2bfloat16(p);
                    }
                    ssum += __shfl_xor(ssum, 1, 64);
                    ssum += __shfl_xor(ssum, 2, 64);
                    ssum += __shfl_xor(ssum, 4, 64);
                    ssum += __shfl_xor(ssum, 8, 64);
                    l_run[t][r] = l_run[t][r] * alpha + ssum;
                    m_run[t][r] = mnew;
#pragma unroll
                    for (int db = 0; db < 8; ++db) oacc[t][db][r] *= alpha;
                }
            }
            asm volatile("s_waitcnt lgkmcnt(0)" ::: "memory");

            // O += P @ V
            __builtin_amdgcn_s_setprio(1);
#pragma unroll
            for (int kk = 0; kk < 2; ++kk) {
                bf16x8 ap = *(const bf16x8*)&Ps[wave][l16][kk * 32 + quad * 8];
                const int voff = ((kk * 4 + quad) ^ swz) * 8;
#pragma unroll
                for (int db = 0; db < 8; ++db) {
                    bf16x8 bv8 = *(const bf16x8*)(Vb + (db * 16 + l16) * 64 + voff);
                    oacc[t][db] = mfma_bf16(ap, bv8, oacc[t][db]);
                }
            }
            __builtin_amdgcn_s_setprio(0);
        }

        // Drains vmcnt(0)+lgkmcnt(0) then barriers: prefetch for tile st+1
        // has landed, and every wave is done reading buf[bi] before the
        // next iteration's STAGE overwrites it.
        __syncthreads();
    }

#pragma unroll
    for (int t = 0; t < 2; ++t) {
        const int q0t = t ? q0A : q0B;
#pragma unroll
        for (int r = 0; r < 4; ++r) {
            const float inv = 1.0f / l_run[t][r];
            const int qg = q0t + qw + quad * 4 + r;
#pragma unroll
            for (int db = 0; db < 8; ++db)
                Og[(size_t)qg * DQ + db * 16 + l16] = __float2bfloat16(oacc[t][db][r] * inv);
        }
    }
}

extern "C" void kernel_launch(void* const* d_in, const int* in_sizes, int n_in,
                              void* d_out, int out_size, void* d_ws, size_t ws_size,
                              hipStream_t stream)
{
    const float* hs = (const float*)d_in[0];
    const float* Wq = (const float*)d_in[1];
    const float* bq = (const float*)d_in[2];
    const float* Wk = (const float*)d_in[3];
    const float* bk = (const float*)d_in[4];
    const float* Wv = (const float*)d_in[5];
    const float* bv = (const float*)d_in[6];
    const float* Wo = (const float*)d_in[7];
    const float* bo = (const float*)d_in[8];
    float* out = (float*)d_out;

    const int M  = 4096;         // B*T tokens
    const int D  = 4096;
    const int DK = 1024;         // G*d
    const size_t SZ_D  = (size_t)M * D;
    const size_t SZ_K  = (size_t)M * DK;

    bf16* hsb  = (bf16*)d_ws;            // [M][D]
    bf16* Wqb  = hsb  + SZ_D;            // [D][D]
    bf16* Wkb  = Wqb  + SZ_D;            // [DK][D]
    bf16* Wvb  = Wkb  + SZ_K;            // [DK][D]
    bf16* Wob  = Wvb  + SZ_K;            // [D][D]
    bf16* q_buf = Wob + SZ_D;            // [M][D]
    bf16* k_buf = q_buf + SZ_D;          // [M][DK]
    bf16* vt_buf = Wqb;                  // ALIAS: Wq consumed before KV-gemm writes vt
    bf16* o_buf  = hsb;                  // ALIAS: hs consumed before attn writes o

    dim3 blk(256);
    const int CB = 256;
    cvt_f32_bf16<<<(int)(SZ_D / 4 + CB - 1) / CB, CB, 0, stream>>>(hs, hsb, (int)SZ_D);
    cvt_f32_bf16<<<(int)(SZ_D / 4 + CB - 1) / CB, CB, 0, stream>>>(Wq, Wqb, (int)SZ_D);
    cvt_f32_bf16<<<(int)(SZ_K / 4 + CB - 1) / CB, CB, 0, stream>>>(Wk, Wkb, (int)SZ_K);
    cvt_f32_bf16<<<(int)(SZ_K / 4 + CB - 1) / CB, CB, 0, stream>>>(Wv, Wvb, (int)SZ_K);
    cvt_f32_bf16<<<(int)(SZ_D / 4 + CB - 1) / CB, CB, 0, stream>>>(Wo, Wob, (int)SZ_D);

    const float scale = 0.08838834764831845f;  // 1/sqrt(128), folded into Q
    gemm_bt_bias<0><<<dim3(M / 128, D / 128), blk, 0, stream>>>(hsb, Wqb, bq, q_buf, M, D, D, scale);
    gemm_kv<<<dim3(M / 128, 16), blk, 0, stream>>>(hsb, Wkb, Wvb, bk, bv, k_buf, vt_buf, M, D);
    attn_fwd<<<dim3(16, 64), blk, 0, stream>>>(q_buf, k_buf, vt_buf, o_buf);
    gemm_bt_bias<1><<<dim3(M / 128, D / 128), blk, 0, stream>>>(o_buf, Wob, bo, out, M, D, D, 1.0f);
}

// Round 4
// 767.880 us; speedup vs baseline: 1.0998x; 1.0998x over previous
//
#include <hip/hip_runtime.h>
#include <hip/hip_bf16.h>
#include <cstdint>
#include <cstddef>

using bf16 = __hip_bfloat16;
typedef __attribute__((ext_vector_type(8))) short bf16x8;
typedef __attribute__((ext_vector_type(4))) float floatx4;

#define GLOBAL_AS __attribute__((address_space(1)))
#define LDS_AS    __attribute__((address_space(3)))

__device__ __forceinline__ void async_copy16(void* lds, const void* g) {
    __builtin_amdgcn_global_load_lds((GLOBAL_AS void*)(g), (LDS_AS void*)(lds), 16, 0, 0);
}

__device__ __forceinline__ floatx4 mfma_bf16(bf16x8 a, bf16x8 b, floatx4 c) {
    return __builtin_amdgcn_mfma_f32_16x16x32_bf16(a, b, c, 0, 0, 0);
}

// fp32 -> bf16 elementwise, 4 elements/thread. n must be a multiple of 4.
__global__ void cvt_f32_bf16(const float* __restrict__ src, bf16* __restrict__ dst, int n) {
    int i = (blockIdx.x * blockDim.x + threadIdx.x) * 4;
    if (i < n) {
        float4 v = *(const float4*)(src + i);
        __align__(8) bf16 t[4];
        t[0] = __float2bfloat16(v.x);
        t[1] = __float2bfloat16(v.y);
        t[2] = __float2bfloat16(v.z);
        t[3] = __float2bfloat16(v.w);
        *(short4*)(dst + i) = *(const short4*)t;
    }
}

// C[m,n] = (sum_k A[m,k] * W[n,k] + bias[n]) * cscale.   (bias is fp32)
// OUTF==0: C bf16 [M][N] row-major; OUTF==1: C fp32 [M][N] row-major.
// cscale folds the attention 1/sqrt(d) into the Q projection for free.
template <int OUTF>
__global__ __launch_bounds__(256, 3) void gemm_bt_bias(
    const bf16* __restrict__ A, const bf16* __restrict__ W,
    const float* __restrict__ bias, void* __restrict__ Cv,
    int M, int N, int K, float cscale)
{
    __shared__ __align__(16) bf16 As[128 * 32];
    __shared__ __align__(16) bf16 Ws[128 * 32];

    const int tid  = threadIdx.x;
    const int lane = tid & 63;
    const int wave = tid >> 6;
    const int quad = lane >> 4;
    const int l16  = lane & 15;
    const int wm = (wave >> 1) * 64;
    const int wn = (wave & 1) * 64;

    const int bm = blockIdx.x;
    const int bn = blockIdx.y;

    floatx4 acc[4][4];
#pragma unroll
    for (int i = 0; i < 4; ++i)
#pragma unroll
        for (int j = 0; j < 4; ++j) acc[i][j] = (floatx4){0.f, 0.f, 0.f, 0.f};

    const int srow = tid >> 2;
    const int scol = (tid & 3) * 8;
    const bf16* gA = A + (size_t)(bm * 128 + srow) * K + scol;
    const bf16* gW = W + (size_t)(bn * 128 + srow) * K + scol;
    bf16* lA0 = As + tid * 8;
    bf16* lA1 = As + 2048 + tid * 8;
    bf16* lW0 = Ws + tid * 8;
    bf16* lW1 = Ws + 2048 + tid * 8;
    const size_t skip = (size_t)64 * K;

    const int kt_n = K >> 5;
    for (int kt = 0; kt < kt_n; ++kt) {
        __syncthreads();
        const bf16* ga = gA + kt * 32;
        const bf16* gw = gW + kt * 32;
        async_copy16(lA0, ga);
        async_copy16(lA1, ga + skip);
        async_copy16(lW0, gw);
        async_copy16(lW1, gw + skip);
        __syncthreads();

        bf16x8 af[4], bfr[4];
#pragma unroll
        for (int mi = 0; mi < 4; ++mi)
            af[mi] = *(const bf16x8*)(As + (wm + mi * 16 + l16) * 32 + quad * 8);
#pragma unroll
        for (int ni = 0; ni < 4; ++ni)
            bfr[ni] = *(const bf16x8*)(Ws + (wn + ni * 16 + l16) * 32 + quad * 8);
#pragma unroll
        for (int mi = 0; mi < 4; ++mi)
#pragma unroll
            for (int ni = 0; ni < 4; ++ni)
                acc[mi][ni] = mfma_bf16(af[mi], bfr[ni], acc[mi][ni]);
    }

#pragma unroll
    for (int mi = 0; mi < 4; ++mi) {
        const int row0 = bm * 128 + wm + mi * 16 + quad * 4;
#pragma unroll
        for (int ni = 0; ni < 4; ++ni) {
            const int col = bn * 128 + wn + ni * 16 + l16;
            const float bv = bias[col];
            if (OUTF) {
                float* C = (float*)Cv;
#pragma unroll
                for (int r = 0; r < 4; ++r)
                    C[(size_t)(row0 + r) * N + col] = (acc[mi][ni][r] + bv) * cscale;
            } else {
                bf16* C = (bf16*)Cv;
#pragma unroll
                for (int r = 0; r < 4; ++r)
                    C[(size_t)(row0 + r) * N + col] = __float2bfloat16((acc[mi][ni][r] + bv) * cscale);
            }
        }
    }
}

// Fused K+V projection. Logical N=2048: bn<8 -> K rows (k_buf row-major
// [M][1024] bf16); bn>=8 -> V rows (vt [B][1024][T] transposed bf16 store).
__global__ __launch_bounds__(256, 3) void gemm_kv(
    const bf16* __restrict__ A,
    const bf16* __restrict__ Wk, const bf16* __restrict__ Wv,
    const float* __restrict__ bk, const float* __restrict__ bv,
    bf16* __restrict__ kout, bf16* __restrict__ vt,
    int M, int K)
{
    __shared__ __align__(16) bf16 As[128 * 32];
    __shared__ __align__(16) bf16 Ws[128 * 32];

    const int tid  = threadIdx.x;
    const int lane = tid & 63;
    const int wave = tid >> 6;
    const int quad = lane >> 4;
    const int l16  = lane & 15;
    const int wm = (wave >> 1) * 64;
    const int wn = (wave & 1) * 64;

    const int bm = blockIdx.x;
    const int bn = blockIdx.y;
    const bool isK = (bn < 8);
    const int nb = isK ? bn : (bn - 8);
    const bf16* Wsel  = isK ? Wk : Wv;
    const float* bsel = isK ? bk : bv;

    floatx4 acc[4][4];
#pragma unroll
    for (int i = 0; i < 4; ++i)
#pragma unroll
        for (int j = 0; j < 4; ++j) acc[i][j] = (floatx4){0.f, 0.f, 0.f, 0.f};

    const int srow = tid >> 2;
    const int scol = (tid & 3) * 8;
    const bf16* gA = A    + (size_t)(bm * 128 + srow) * K + scol;
    const bf16* gW = Wsel + (size_t)(nb * 128 + srow) * K + scol;
    bf16* lA0 = As + tid * 8;
    bf16* lA1 = As + 2048 + tid * 8;
    bf16* lW0 = Ws + tid * 8;
    bf16* lW1 = Ws + 2048 + tid * 8;
    const size_t skip = (size_t)64 * K;

    const int kt_n = K >> 5;
    for (int kt = 0; kt < kt_n; ++kt) {
        __syncthreads();
        const bf16* ga = gA + kt * 32;
        const bf16* gw = gW + kt * 32;
        async_copy16(lA0, ga);
        async_copy16(lA1, ga + skip);
        async_copy16(lW0, gw);
        async_copy16(lW1, gw + skip);
        __syncthreads();

        bf16x8 af[4], bfr[4];
#pragma unroll
        for (int mi = 0; mi < 4; ++mi)
            af[mi] = *(const bf16x8*)(As + (wm + mi * 16 + l16) * 32 + quad * 8);
#pragma unroll
        for (int ni = 0; ni < 4; ++ni)
            bfr[ni] = *(const bf16x8*)(Ws + (wn + ni * 16 + l16) * 32 + quad * 8);
#pragma unroll
        for (int mi = 0; mi < 4; ++mi)
#pragma unroll
            for (int ni = 0; ni < 4; ++ni)
                acc[mi][ni] = mfma_bf16(af[mi], bfr[ni], acc[mi][ni]);
    }

#pragma unroll
    for (int mi = 0; mi < 4; ++mi) {
        const int row0 = bm * 128 + wm + mi * 16 + quad * 4;
#pragma unroll
        for (int ni = 0; ni < 4; ++ni) {
            const int col = nb * 128 + wn + ni * 16 + l16;
            const float bvv = bsel[col];
            if (isK) {
#pragma unroll
                for (int r = 0; r < 4; ++r)
                    kout[(size_t)(row0 + r) * 1024 + col] = __float2bfloat16(acc[mi][ni][r] + bvv);
            } else {
                __align__(8) bf16 tmp[4];
#pragma unroll
                for (int r = 0; r < 4; ++r) tmp[r] = __float2bfloat16(acc[mi][ni][r] + bvv);
                const int b  = row0 >> 11;      // T = 2048
                const int t0 = row0 & 2047;
                bf16* dst = vt + ((size_t)(b * 1024 + col)) * 2048 + t0;
                *(short4*)dst = *(const short4*)tmp;
            }
        }
    }
}

// Flash attention, causal, balanced q-tile pairing.
// Block (qi, bh) handles q-tiles qtB=31-qi (large) and qtA=qi (small).
// v8: swapped QK^T (S^T = mfma(K,Q)) -> per-lane-row softmax.
//  - Each lane holds the full 16 s-values of ONE q-row (q = l16) in
//    registers: row max/sum are in-lane trees + 2 shfl_xor (16,32)
//    instead of 4 rows x 8 shuffles; P stored as 4x ds_write_b64
//    (s-contiguous) instead of 16 scalar ds_write_b16.
//  - alpha / 1/l redistributed to oacc rows (quad*4+r) via 4 __shfl.
//  - setprio and defer-max REVERTED (round-3 regression: bundled, hurt).
//  - scale stays folded into the Q projection.
//  - (from v6) Q in registers; K/V double-buffered global_load_lds DMA,
//    prefetch at top of iteration; both-sides XOR swizzle.
__global__ __launch_bounds__(256, 2) void attn_fwd(
    const bf16* __restrict__ qb, const bf16* __restrict__ kb,
    const bf16* __restrict__ vtb, bf16* __restrict__ ob)
{
    constexpr int T  = 2048;
    constexpr int DQ = 4096;
    constexpr int DK = 1024;

    __shared__ __align__(16) bf16 Ks[2][64 * 128];   // [buf][row 0..63][col granule], linear
    __shared__ __align__(16) bf16 Vs[2][128 * 64];   // [buf][d 0..127][s granule], linear
    __shared__ __align__(16) bf16 Ps[4][16][72];     // per-wave P tile [q][s]

    const int tid  = threadIdx.x;
    const int lane = tid & 63;
    const int wave = tid >> 6;
    const int quad = lane >> 4;
    const int l16  = lane & 15;
    const int swz  = l16 & 7;

    const int qi = blockIdx.x;    // 0..15
    const int bh = blockIdx.y;
    const int b  = bh >> 5;
    const int h  = bh & 31;
    const int g  = h >> 2;        // GROUP = 4
    const int qtB = 31 - qi;      // large tile
    const int qtA = qi;           // small tile
    const int q0B = qtB * 64;
    const int q0A = qtA * 64;
    const int qw = wave * 16;

    const bf16* Qg = qb  + (size_t)b * T * DQ + (size_t)h * 128;
    const bf16* Kg = kb  + (size_t)b * T * DK + (size_t)g * 128;
    const bf16* Vg = vtb + ((size_t)b * DK + g * 128) * T;
    bf16*       Og = ob  + (size_t)b * T * DQ + (size_t)h * 128;

    // ---- Q fragments -> registers (16 q-rows per wave per tile) ----
    bf16x8 qf[2][4];
    {
        const size_t rB = (size_t)(q0B + qw + l16) * DQ;
        const size_t rA = (size_t)(q0A + qw + l16) * DQ;
#pragma unroll
        for (int kk = 0; kk < 4; ++kk) {
            qf[0][kk] = *(const bf16x8*)(Qg + rB + kk * 32 + quad * 8);
            qf[1][kk] = *(const bf16x8*)(Qg + rA + kk * 32 + quad * 8);
        }
    }

    // staging geometry (per-thread, 16B granules)
    const int krow_l = tid >> 4;   // K tile: row = i*16 + krow_l, col16 = tid&15
    const int kc16   = tid & 15;
    const int vrow_l = tid >> 3;   // V tile: row = i*32 + vrow_l, col16 = tid&7
    const int vc16   = tid & 7;

    // Stage tile st_ into buffer bi_: 8 global_load_lds per thread.
    // LDS dest is LINEAR (base + lane*16B per wave); global source column
    // is pre-swizzled with (row & 7).
    auto STAGE = [&](int st_, int bi_) {
        const int s0_ = st_ * 64;
        bf16* kbp = &Ks[bi_][0];
        bf16* vbp = &Vs[bi_][0];
#pragma unroll
        for (int i = 0; i < 4; ++i) {
            const int r = i * 16 + krow_l;
            async_copy16(kbp + (i * 256 + tid) * 8,
                         Kg + (size_t)(s0_ + r) * DK + ((kc16 ^ (r & 7)) * 8));
        }
#pragma unroll
        for (int i = 0; i < 4; ++i) {
            const int r = i * 32 + vrow_l;
            async_copy16(vbp + (i * 256 + tid) * 8,
                         Vg + (size_t)r * T + s0_ + ((vc16 ^ (r & 7)) * 8));
        }
    };

    floatx4 oacc[2][8];
#pragma unroll
    for (int t = 0; t < 2; ++t)
#pragma unroll
        for (int i = 0; i < 8; ++i) oacc[t][i] = (floatx4){0.f, 0.f, 0.f, 0.f};
    float m_run[2], l_run[2];
#pragma unroll
    for (int t = 0; t < 2; ++t) { m_run[t] = -1e30f; l_run[t] = 0.f; }

    // broadcast source lane for redistributing per-q (l16-indexed) scalars
    // to oacc rows (quad*4+r): src = quad*16 + quad*4 + r
    const int bsrc = (lane & 48) + quad * 4;

    STAGE(0, 0);
    __syncthreads();   // drains vmcnt: tile 0 resident in LDS for all waves

    for (int st = 0; st <= qtB; ++st) {
        const int bi = st & 1;
        const int s0 = st * 64;

        if (st < qtB) STAGE(st + 1, bi ^ 1);   // prefetch next tile into other buffer

        const bf16* Kb = &Ks[bi][0];
        const bf16* Vb = &Vs[bi][0];

        const int ntile = (st <= qtA) ? 2 : 1;
#pragma unroll
        for (int t = 0; t < 2; ++t) {
            if (t >= ntile) break;
            const int q0t  = t ? q0A : q0B;
            const int qt_t = t ? qtA : qtB;

            // S^T[64s][16q] via swapped operands: each lane holds 16
            // s-values (ni*16 + quad*4 + r) of its own q-row (q = l16).
            floatx4 sacc[4];
#pragma unroll
            for (int i = 0; i < 4; ++i) sacc[i] = (floatx4){0.f, 0.f, 0.f, 0.f};
#pragma unroll
            for (int kk = 0; kk < 4; ++kk) {
                const int koff = ((kk * 4 + quad) ^ swz) * 8;
                const bf16x8 qv = qf[t][kk];
#pragma unroll
                for (int ni = 0; ni < 4; ++ni) {
                    bf16x8 kf = *(const bf16x8*)(Kb + (ni * 16 + l16) * 128 + koff);
                    sacc[ni] = mfma_bf16(kf, qv, sacc[ni]);
                }
            }

            const bool diag = (st == qt_t);
            const int qg = q0t + qw + l16;           // this lane's q-row
            float sv[4][4];
#pragma unroll
            for (int ni = 0; ni < 4; ++ni)
#pragma unroll
                for (int r = 0; r < 4; ++r) {
                    float x = sacc[ni][r];
                    if (diag && (s0 + ni * 16 + quad * 4 + r) > qg) x = -1e30f;
                    sv[ni][r] = x;
                }

            // row max: in-lane tree over 16, then combine the 4 quads
            float pm[4];
#pragma unroll
            for (int ni = 0; ni < 4; ++ni)
                pm[ni] = fmaxf(fmaxf(sv[ni][0], sv[ni][1]), fmaxf(sv[ni][2], sv[ni][3]));
            float mx = fmaxf(fmaxf(pm[0], pm[1]), fmaxf(pm[2], pm[3]));
            mx = fmaxf(mx, __shfl_xor(mx, 16, 64));
            mx = fmaxf(mx, __shfl_xor(mx, 32, 64));

            const float mold  = m_run[t];
            const float mnew  = fmaxf(mold, mx);
            const float alpha = __expf(mold - mnew);
            m_run[t] = mnew;

            // P = exp(S - mnew); packed b64 stores (4 s-contiguous bf16)
            float ssum = 0.f;
#pragma unroll
            for (int ni = 0; ni < 4; ++ni) {
                __align__(8) bf16 pb[4];
#pragma unroll
                for (int r = 0; r < 4; ++r) {
                    float p = __expf(sv[ni][r] - mnew);
                    ssum += p;
                    pb[r] = __float2bfloat16(p);
                }
                *(short4*)&Ps[wave][l16][ni * 16 + quad * 4] = *(const short4*)pb;
            }
            ssum += __shfl_xor(ssum, 16, 64);
            ssum += __shfl_xor(ssum, 32, 64);
            l_run[t] = l_run[t] * alpha + ssum;

            // redistribute alpha (indexed by q=l16) to oacc rows quad*4+r
            float ar[4];
#pragma unroll
            for (int r = 0; r < 4; ++r) ar[r] = __shfl(alpha, bsrc + r, 64);
#pragma unroll
            for (int db = 0; db < 8; ++db)
#pragma unroll
                for (int r = 0; r < 4; ++r) oacc[t][db][r] *= ar[r];

            asm volatile("s_waitcnt lgkmcnt(0)" ::: "memory");

            // O += P @ V
#pragma unroll
            for (int kk = 0; kk < 2; ++kk) {
                bf16x8 ap = *(const bf16x8*)&Ps[wave][l16][kk * 32 + quad * 8];
                const int voff = ((kk * 4 + quad) ^ swz) * 8;
#pragma unroll
                for (int db = 0; db < 8; ++db) {
                    bf16x8 bv8 = *(const bf16x8*)(Vb + (db * 16 + l16) * 64 + voff);
                    oacc[t][db] = mfma_bf16(ap, bv8, oacc[t][db]);
                }
            }
        }

        // Drains vmcnt(0)+lgkmcnt(0) then barriers: prefetch for tile st+1
        // has landed, and every wave is done reading buf[bi] before the
        // next iteration's STAGE overwrites it.
        __syncthreads();
    }

#pragma unroll
    for (int t = 0; t < 2; ++t) {
        const int q0t = t ? q0A : q0B;
        const float linv = 1.0f / l_run[t];
        float ir[4];
#pragma unroll
        for (int r = 0; r < 4; ++r) ir[r] = __shfl(linv, bsrc + r, 64);
#pragma unroll
        for (int r = 0; r < 4; ++r) {
            const int qg = q0t + qw + quad * 4 + r;
#pragma unroll
            for (int db = 0; db < 8; ++db)
                Og[(size_t)qg * DQ + db * 16 + l16] = __float2bfloat16(oacc[t][db][r] * ir[r]);
        }
    }
}

extern "C" void kernel_launch(void* const* d_in, const int* in_sizes, int n_in,
                              void* d_out, int out_size, void* d_ws, size_t ws_size,
                              hipStream_t stream)
{
    const float* hs = (const float*)d_in[0];
    const float* Wq = (const float*)d_in[1];
    const float* bq = (const float*)d_in[2];
    const float* Wk = (const float*)d_in[3];
    const float* bk = (const float*)d_in[4];
    const float* Wv = (const float*)d_in[5];
    const float* bv = (const float*)d_in[6];
    const float* Wo = (const float*)d_in[7];
    const float* bo = (const float*)d_in[8];
    float* out = (float*)d_out;

    const int M  = 4096;         // B*T tokens
    const int D  = 4096;
    const int DK = 1024;         // G*d
    const size_t SZ_D  = (size_t)M * D;
    const size_t SZ_K  = (size_t)M * DK;

    bf16* hsb  = (bf16*)d_ws;            // [M][D]
    bf16* Wqb  = hsb  + SZ_D;            // [D][D]
    bf16* Wkb  = Wqb  + SZ_D;            // [DK][D]
    bf16* Wvb  = Wkb  + SZ_K;            // [DK][D]
    bf16* Wob  = Wvb  + SZ_K;            // [D][D]
    bf16* q_buf = Wob + SZ_D;            // [M][D]
    bf16* k_buf = q_buf + SZ_D;          // [M][DK]
    bf16* vt_buf = Wqb;                  // ALIAS: Wq consumed before KV-gemm writes vt
    bf16* o_buf  = hsb;                  // ALIAS: hs consumed before attn writes o

    dim3 blk(256);
    const int CB = 256;
    cvt_f32_bf16<<<(int)(SZ_D / 4 + CB - 1) / CB, CB, 0, stream>>>(hs, hsb, (int)SZ_D);
    cvt_f32_bf16<<<(int)(SZ_D / 4 + CB - 1) / CB, CB, 0, stream>>>(Wq, Wqb, (int)SZ_D);
    cvt_f32_bf16<<<(int)(SZ_K / 4 + CB - 1) / CB, CB, 0, stream>>>(Wk, Wkb, (int)SZ_K);
    cvt_f32_bf16<<<(int)(SZ_K / 4 + CB - 1) / CB, CB, 0, stream>>>(Wv, Wvb, (int)SZ_K);
    cvt_f32_bf16<<<(int)(SZ_D / 4 + CB - 1) / CB, CB, 0, stream>>>(Wo, Wob, (int)SZ_D);

    const float scale = 0.08838834764831845f;  // 1/sqrt(128), folded into Q
    gemm_bt_bias<0><<<dim3(M / 128, D / 128), blk, 0, stream>>>(hsb, Wqb, bq, q_buf, M, D, D, scale);
    gemm_kv<<<dim3(M / 128, 16), blk, 0, stream>>>(hsb, Wkb, Wvb, bk, bv, k_buf, vt_buf, M, D);
    attn_fwd<<<dim3(16, 64), blk, 0, stream>>>(q_buf, k_buf, vt_buf, o_buf);
    gemm_bt_bias<1><<<dim3(M / 128, D / 128), blk, 0, stream>>>(o_buf, Wob, bo, out, M, D, D, 1.0f);
}

// Round 5
// 746.113 us; speedup vs baseline: 1.1319x; 1.0292x over previous
//
#include <hip/hip_runtime.h>
#include <hip/hip_bf16.h>
#include <cstdint>
#include <cstddef>

using bf16 = __hip_bfloat16;
typedef __attribute__((ext_vector_type(8))) short bf16x8;
typedef __attribute__((ext_vector_type(4))) float floatx4;

#define GLOBAL_AS __attribute__((address_space(1)))
#define LDS_AS    __attribute__((address_space(3)))

__device__ __forceinline__ void async_copy16(void* lds, const void* g) {
    __builtin_amdgcn_global_load_lds((GLOBAL_AS void*)(g), (LDS_AS void*)(lds), 16, 0, 0);
}

__device__ __forceinline__ floatx4 mfma_bf16(bf16x8 a, bf16x8 b, floatx4 c) {
    return __builtin_amdgcn_mfma_f32_16x16x32_bf16(a, b, c, 0, 0, 0);
}

// fp32 -> bf16 elementwise, 4 elements/thread. n must be a multiple of 4.
__global__ void cvt_f32_bf16(const float* __restrict__ src, bf16* __restrict__ dst, int n) {
    int i = (blockIdx.x * blockDim.x + threadIdx.x) * 4;
    if (i < n) {
        float4 v = *(const float4*)(src + i);
        __align__(8) bf16 t[4];
        t[0] = __float2bfloat16(v.x);
        t[1] = __float2bfloat16(v.y);
        t[2] = __float2bfloat16(v.z);
        t[3] = __float2bfloat16(v.w);
        *(short4*)(dst + i) = *(const short4*)t;
    }
}

// ===========================================================================
// 256x256 8-phase GEMM (T2+T3+T4+T5): C[m,n] = (sum_k A[m,k]*W[n,k] + b[n])*s
// BM=BN=256, BK=64, 512 threads = 8 waves (2M x 4N), per-wave 128x64 output.
// LDS 128KB: 2 dbuf x {A,B} x 2 halves x [128][64] bf16, granule-XOR swizzle
// (c16 ^= row&7) pre-applied on the GLOBAL source + on the ds_read side,
// linear LDS dest (both-sides-or-neither rule for global_load_lds).
// Per iteration: 2 K-tiles, 8 phases; counted vmcnt(4) only at phases 3/7.
// Staging order (steady state, iter computing kt=2i buf0 / kt+1 buf1):
//   ph0,1: B(kt+1)->buf1   ph2,3: A(kt+2)->buf0
//   ph4,5: B(kt+2)->buf0   ph6,7: A(kt+3)->buf1
// Each region's last reader finished one full barrier before its stage.
// ===========================================================================
#define MMBLK(AF, MB, NB) do {                                                 \
    __builtin_amdgcn_s_setprio(1);                                             \
    _Pragma("unroll") for (int kk = 0; kk < 2; ++kk)                           \
    _Pragma("unroll") for (int mi = 0; mi < 4; ++mi)                           \
    _Pragma("unroll") for (int ni = 0; ni < 2; ++ni)                           \
        acc[(MB) + mi][(NB) + ni] =                                            \
            mfma_bf16(AF[mi][kk], bb[ni][kk], acc[(MB) + mi][(NB) + ni]);      \
    __builtin_amdgcn_s_setprio(0);                                             \
} while (0)

#define BAR()   __builtin_amdgcn_s_barrier()
#define LGKM0() asm volatile("s_waitcnt lgkmcnt(0)" ::: "memory")
#define VM4()   asm volatile("s_waitcnt vmcnt(4)" ::: "memory")
#define VM0()   asm volatile("s_waitcnt vmcnt(0)" ::: "memory")

template <int OUTF>
__global__ __launch_bounds__(512, 2) void gemm256_bt_bias(
    const bf16* __restrict__ A, const bf16* __restrict__ W,
    const float* __restrict__ bias, void* __restrict__ Cv,
    int M, int N, int K, float cscale)
{
    __shared__ __align__(16) bf16 sA[2][2][128 * 64];
    __shared__ __align__(16) bf16 sB[2][2][128 * 64];

    const int tid  = threadIdx.x;
    const int lane = tid & 63;
    const int wave = tid >> 6;       // 0..7
    const int quad = lane >> 4;
    const int l16  = lane & 15;
    const int wmi  = wave >> 2;      // 0..1: A half / output rows wmi*128
    const int wni  = wave & 3;       // 0..3: output cols wni*64; B half = wni>>1

    const int bm = blockIdx.x;
    const int bn = blockIdx.y;

    const int srow = tid >> 3;       // staging granule row (i=0)
    const int sc16 = tid & 7;

    // stage one 128x64 half-tile (2 x global_load_lds / thread, linear dest,
    // source column pre-swizzled with row&7)
    auto STAGE = [&](bf16* dst, const bf16* G, int rowbase, int kt) {
#pragma unroll
        for (int i = 0; i < 2; ++i) {
            const int row = i * 64 + srow;
            async_copy16(dst + (i * 512 + tid) * 8,
                         G + (size_t)(rowbase + row) * K + kt * 64 + ((sc16 ^ (row & 7)) * 8));
        }
    };
    auto LDA = [&](int bi, int mi, int kk) -> bf16x8 {
        const bf16* base = &sA[bi][wmi][0];
        const int r = mi * 16 + l16;
        return *(const bf16x8*)(base + r * 64 + (((kk * 4 + quad) ^ (r & 7)) * 8));
    };
    auto LDB = [&](int bi, int ni, int kk) -> bf16x8 {
        const bf16* base = &sB[bi][wni >> 1][0];
        const int r = (wni & 1) * 64 + ni * 16 + l16;
        return *(const bf16x8*)(base + r * 64 + (((kk * 4 + quad) ^ (r & 7)) * 8));
    };

    floatx4 acc[8][4];
#pragma unroll
    for (int i = 0; i < 8; ++i)
#pragma unroll
        for (int j = 0; j < 4; ++j) acc[i][j] = (floatx4){0.f, 0.f, 0.f, 0.f};

    const int rowA = bm * 256;
    const int rowB = bn * 256;
    const int iters = K >> 7;        // K/128: 2 K-tiles (BK=64) per iter

    // ---- prologue: buf0 <- K-tile 0 (4 half-tiles), buf1 <- A of K-tile 1
    STAGE(&sA[0][0][0], A, rowA + 0,   0);
    STAGE(&sA[0][1][0], A, rowA + 128, 0);
    STAGE(&sB[0][0][0], W, rowB + 0,   0);
    STAGE(&sB[0][1][0], W, rowB + 128, 0);
    STAGE(&sA[1][0][0], A, rowA + 0,   1);
    STAGE(&sA[1][1][0], A, rowA + 128, 1);
    VM4();                            // buf0's 8 loads landed; A(1) in flight
    BAR();

    bf16x8 a0[4][2], a1[4][2], bb[2][2];
    for (int i = 0; i < iters; ++i) {
        const int kt = 2 * i;
        const bool nl = (i + 1 < iters);

        // -- phase 0: read buf0 A(mi0-3)+B(ni0-1); stage B0(kt+1)->buf1
#pragma unroll
        for (int mi = 0; mi < 4; ++mi) { a0[mi][0] = LDA(0, mi, 0); a0[mi][1] = LDA(0, mi, 1); }
#pragma unroll
        for (int ni = 0; ni < 2; ++ni) { bb[ni][0] = LDB(0, ni, 0); bb[ni][1] = LDB(0, ni, 1); }
        STAGE(&sB[1][0][0], W, rowB + 0, kt + 1);
        BAR(); LGKM0();
        MMBLK(a0, 0, 0);
        BAR();
        // -- phase 1: read buf0 A(mi4-7); stage B1(kt+1)->buf1
#pragma unroll
        for (int mi = 0; mi < 4; ++mi) { a1[mi][0] = LDA(0, mi + 4, 0); a1[mi][1] = LDA(0, mi + 4, 1); }
        STAGE(&sB[1][1][0], W, rowB + 128, kt + 1);
        BAR(); LGKM0();
        MMBLK(a1, 4, 0);
        BAR();
        // -- phase 2: read buf0 B(ni2-3); stage A0(kt+2)->buf0
#pragma unroll
        for (int ni = 0; ni < 2; ++ni) { bb[ni][0] = LDB(0, ni + 2, 0); bb[ni][1] = LDB(0, ni + 2, 1); }
        if (nl) STAGE(&sA[0][0][0], A, rowA + 0, kt + 2);
        BAR(); LGKM0();
        MMBLK(a0, 0, 2);
        BAR();
        // -- phase 3: stage A1(kt+2)->buf0; counted vmcnt (buf1(kt+1) landed)
        if (nl) { STAGE(&sA[0][1][0], A, rowA + 128, kt + 2); VM4(); }
        else    { VM0(); }
        BAR();
        MMBLK(a1, 4, 2);
        BAR();
        // -- phase 4: read buf1 A(mi0-3)+B(ni0-1); stage B0(kt+2)->buf0
#pragma unroll
        for (int mi = 0; mi < 4; ++mi) { a0[mi][0] = LDA(1, mi, 0); a0[mi][1] = LDA(1, mi, 1); }
#pragma unroll
        for (int ni = 0; ni < 2; ++ni) { bb[ni][0] = LDB(1, ni, 0); bb[ni][1] = LDB(1, ni, 1); }
        if (nl) STAGE(&sB[0][0][0], W, rowB + 0, kt + 2);
        BAR(); LGKM0();
        MMBLK(a0, 0, 0);
        BAR();
        // -- phase 5: read buf1 A(mi4-7); stage B1(kt+2)->buf0
#pragma unroll
        for (int mi = 0; mi < 4; ++mi) { a1[mi][0] = LDA(1, mi + 4, 0); a1[mi][1] = LDA(1, mi + 4, 1); }
        if (nl) STAGE(&sB[0][1][0], W, rowB + 128, kt + 2);
        BAR(); LGKM0();
        MMBLK(a1, 4, 0);
        BAR();
        // -- phase 6: read buf1 B(ni2-3); stage A0(kt+3)->buf1
#pragma unroll
        for (int ni = 0; ni < 2; ++ni) { bb[ni][0] = LDB(1, ni + 2, 0); bb[ni][1] = LDB(1, ni + 2, 1); }
        if (nl) STAGE(&sA[1][0][0], A, rowA + 0, kt + 3);
        BAR(); LGKM0();
        MMBLK(a0, 0, 2);
        BAR();
        // -- phase 7: stage A1(kt+3)->buf1; counted vmcnt (buf0(kt+2) landed)
        if (nl) { STAGE(&sA[1][1][0], A, rowA + 128, kt + 3); VM4(); }
        BAR();
        MMBLK(a1, 4, 2);
        BAR();
    }

    // ---- epilogue
#pragma unroll
    for (int mi = 0; mi < 8; ++mi) {
        const int row0 = bm * 256 + wmi * 128 + mi * 16 + quad * 4;
#pragma unroll
        for (int ni = 0; ni < 4; ++ni) {
            const int col = bn * 256 + wni * 64 + ni * 16 + l16;
            const float bv = bias[col];
            if (OUTF) {
                float* C = (float*)Cv;
#pragma unroll
                for (int r = 0; r < 4; ++r)
                    C[(size_t)(row0 + r) * N + col] = (acc[mi][ni][r] + bv) * cscale;
            } else {
                bf16* C = (bf16*)Cv;
#pragma unroll
                for (int r = 0; r < 4; ++r)
                    C[(size_t)(row0 + r) * N + col] = __float2bfloat16((acc[mi][ni][r] + bv) * cscale);
            }
        }
    }
}

// Fused K+V projection (128^2 structure: grid 32x16 = 512 blocks keeps all
// CUs busy; a 256^2 port would only fill 128 of 256 CUs). Logical N=2048:
// bn<8 -> K rows (k_buf row-major [M][1024]); bn>=8 -> V rows (vt transposed).
__global__ __launch_bounds__(256, 3) void gemm_kv(
    const bf16* __restrict__ A,
    const bf16* __restrict__ Wk, const bf16* __restrict__ Wv,
    const float* __restrict__ bk, const float* __restrict__ bv,
    bf16* __restrict__ kout, bf16* __restrict__ vt,
    int M, int K)
{
    __shared__ __align__(16) bf16 As[128 * 32];
    __shared__ __align__(16) bf16 Ws[128 * 32];

    const int tid  = threadIdx.x;
    const int lane = tid & 63;
    const int wave = tid >> 6;
    const int quad = lane >> 4;
    const int l16  = lane & 15;
    const int wm = (wave >> 1) * 64;
    const int wn = (wave & 1) * 64;

    const int bm = blockIdx.x;
    const int bn = blockIdx.y;
    const bool isK = (bn < 8);
    const int nb = isK ? bn : (bn - 8);
    const bf16* Wsel  = isK ? Wk : Wv;
    const float* bsel = isK ? bk : bv;

    floatx4 acc[4][4];
#pragma unroll
    for (int i = 0; i < 4; ++i)
#pragma unroll
        for (int j = 0; j < 4; ++j) acc[i][j] = (floatx4){0.f, 0.f, 0.f, 0.f};

    const int srow = tid >> 2;
    const int scol = (tid & 3) * 8;
    const bf16* gA = A    + (size_t)(bm * 128 + srow) * K + scol;
    const bf16* gW = Wsel + (size_t)(nb * 128 + srow) * K + scol;
    bf16* lA0 = As + tid * 8;
    bf16* lA1 = As + 2048 + tid * 8;
    bf16* lW0 = Ws + tid * 8;
    bf16* lW1 = Ws + 2048 + tid * 8;
    const size_t skip = (size_t)64 * K;

    const int kt_n = K >> 5;
    for (int kt = 0; kt < kt_n; ++kt) {
        __syncthreads();
        const bf16* ga = gA + kt * 32;
        const bf16* gw = gW + kt * 32;
        async_copy16(lA0, ga);
        async_copy16(lA1, ga + skip);
        async_copy16(lW0, gw);
        async_copy16(lW1, gw + skip);
        __syncthreads();

        bf16x8 af[4], bfr[4];
#pragma unroll
        for (int mi = 0; mi < 4; ++mi)
            af[mi] = *(const bf16x8*)(As + (wm + mi * 16 + l16) * 32 + quad * 8);
#pragma unroll
        for (int ni = 0; ni < 4; ++ni)
            bfr[ni] = *(const bf16x8*)(Ws + (wn + ni * 16 + l16) * 32 + quad * 8);
#pragma unroll
        for (int mi = 0; mi < 4; ++mi)
#pragma unroll
            for (int ni = 0; ni < 4; ++ni)
                acc[mi][ni] = mfma_bf16(af[mi], bfr[ni], acc[mi][ni]);
    }

#pragma unroll
    for (int mi = 0; mi < 4; ++mi) {
        const int row0 = bm * 128 + wm + mi * 16 + quad * 4;
#pragma unroll
        for (int ni = 0; ni < 4; ++ni) {
            const int col = nb * 128 + wn + ni * 16 + l16;
            const float bvv = bsel[col];
            if (isK) {
#pragma unroll
                for (int r = 0; r < 4; ++r)
                    kout[(size_t)(row0 + r) * 1024 + col] = __float2bfloat16(acc[mi][ni][r] + bvv);
            } else {
                __align__(8) bf16 tmp[4];
#pragma unroll
                for (int r = 0; r < 4; ++r) tmp[r] = __float2bfloat16(acc[mi][ni][r] + bvv);
                const int b  = row0 >> 11;      // T = 2048
                const int t0 = row0 & 2047;
                bf16* dst = vt + ((size_t)(b * 1024 + col)) * 2048 + t0;
                *(short4*)dst = *(const short4*)tmp;
            }
        }
    }
}

// Flash attention, causal, balanced q-tile pairing. (v8, unchanged: swapped
// QK^T per-lane-row softmax; Q in registers; K/V double-buffered DMA with
// top-of-iteration prefetch; both-sides XOR swizzle.)
__global__ __launch_bounds__(256, 2) void attn_fwd(
    const bf16* __restrict__ qb, const bf16* __restrict__ kb,
    const bf16* __restrict__ vtb, bf16* __restrict__ ob)
{
    constexpr int T  = 2048;
    constexpr int DQ = 4096;
    constexpr int DK = 1024;

    __shared__ __align__(16) bf16 Ks[2][64 * 128];
    __shared__ __align__(16) bf16 Vs[2][128 * 64];
    __shared__ __align__(16) bf16 Ps[4][16][72];

    const int tid  = threadIdx.x;
    const int lane = tid & 63;
    const int wave = tid >> 6;
    const int quad = lane >> 4;
    const int l16  = lane & 15;
    const int swz  = l16 & 7;

    const int qi = blockIdx.x;    // 0..15
    const int bh = blockIdx.y;
    const int b  = bh >> 5;
    const int h  = bh & 31;
    const int g  = h >> 2;        // GROUP = 4
    const int qtB = 31 - qi;      // large tile
    const int qtA = qi;           // small tile
    const int q0B = qtB * 64;
    const int q0A = qtA * 64;
    const int qw = wave * 16;

    const bf16* Qg = qb  + (size_t)b * T * DQ + (size_t)h * 128;
    const bf16* Kg = kb  + (size_t)b * T * DK + (size_t)g * 128;
    const bf16* Vg = vtb + ((size_t)b * DK + g * 128) * T;
    bf16*       Og = ob  + (size_t)b * T * DQ + (size_t)h * 128;

    bf16x8 qf[2][4];
    {
        const size_t rB = (size_t)(q0B + qw + l16) * DQ;
        const size_t rA = (size_t)(q0A + qw + l16) * DQ;
#pragma unroll
        for (int kk = 0; kk < 4; ++kk) {
            qf[0][kk] = *(const bf16x8*)(Qg + rB + kk * 32 + quad * 8);
            qf[1][kk] = *(const bf16x8*)(Qg + rA + kk * 32 + quad * 8);
        }
    }

    const int krow_l = tid >> 4;
    const int kc16   = tid & 15;
    const int vrow_l = tid >> 3;
    const int vc16   = tid & 7;

    auto STAGE = [&](int st_, int bi_) {
        const int s0_ = st_ * 64;
        bf16* kbp = &Ks[bi_][0];
        bf16* vbp = &Vs[bi_][0];
#pragma unroll
        for (int i = 0; i < 4; ++i) {
            const int r = i * 16 + krow_l;
            async_copy16(kbp + (i * 256 + tid) * 8,
                         Kg + (size_t)(s0_ + r) * DK + ((kc16 ^ (r & 7)) * 8));
        }
#pragma unroll
        for (int i = 0; i < 4; ++i) {
            const int r = i * 32 + vrow_l;
            async_copy16(vbp + (i * 256 + tid) * 8,
                         Vg + (size_t)r * T + s0_ + ((vc16 ^ (r & 7)) * 8));
        }
    };

    floatx4 oacc[2][8];
#pragma unroll
    for (int t = 0; t < 2; ++t)
#pragma unroll
        for (int i = 0; i < 8; ++i) oacc[t][i] = (floatx4){0.f, 0.f, 0.f, 0.f};
    float m_run[2], l_run[2];
#pragma unroll
    for (int t = 0; t < 2; ++t) { m_run[t] = -1e30f; l_run[t] = 0.f; }

    const int bsrc = (lane & 48) + quad * 4;

    STAGE(0, 0);
    __syncthreads();

    for (int st = 0; st <= qtB; ++st) {
        const int bi = st & 1;
        const int s0 = st * 64;

        if (st < qtB) STAGE(st + 1, bi ^ 1);

        const bf16* Kb = &Ks[bi][0];
        const bf16* Vb = &Vs[bi][0];

        const int ntile = (st <= qtA) ? 2 : 1;
#pragma unroll
        for (int t = 0; t < 2; ++t) {
            if (t >= ntile) break;
            const int q0t  = t ? q0A : q0B;
            const int qt_t = t ? qtA : qtB;

            floatx4 sacc[4];
#pragma unroll
            for (int i = 0; i < 4; ++i) sacc[i] = (floatx4){0.f, 0.f, 0.f, 0.f};
#pragma unroll
            for (int kk = 0; kk < 4; ++kk) {
                const int koff = ((kk * 4 + quad) ^ swz) * 8;
                const bf16x8 qv = qf[t][kk];
#pragma unroll
                for (int ni = 0; ni < 4; ++ni) {
                    bf16x8 kf = *(const bf16x8*)(Kb + (ni * 16 + l16) * 128 + koff);
                    sacc[ni] = mfma_bf16(kf, qv, sacc[ni]);
                }
            }

            const bool diag = (st == qt_t);
            const int qg = q0t + qw + l16;
            float sv[4][4];
#pragma unroll
            for (int ni = 0; ni < 4; ++ni)
#pragma unroll
                for (int r = 0; r < 4; ++r) {
                    float x = sacc[ni][r];
                    if (diag && (s0 + ni * 16 + quad * 4 + r) > qg) x = -1e30f;
                    sv[ni][r] = x;
                }

            float pm[4];
#pragma unroll
            for (int ni = 0; ni < 4; ++ni)
                pm[ni] = fmaxf(fmaxf(sv[ni][0], sv[ni][1]), fmaxf(sv[ni][2], sv[ni][3]));
            float mx = fmaxf(fmaxf(pm[0], pm[1]), fmaxf(pm[2], pm[3]));
            mx = fmaxf(mx, __shfl_xor(mx, 16, 64));
            mx = fmaxf(mx, __shfl_xor(mx, 32, 64));

            const float mold  = m_run[t];
            const float mnew  = fmaxf(mold, mx);
            const float alpha = __expf(mold - mnew);
            m_run[t] = mnew;

            float ssum = 0.f;
#pragma unroll
            for (int ni = 0; ni < 4; ++ni) {
                __align__(8) bf16 pb[4];
#pragma unroll
                for (int r = 0; r < 4; ++r) {
                    float p = __expf(sv[ni][r] - mnew);
                    ssum += p;
                    pb[r] = __float2bfloat16(p);
                }
                *(short4*)&Ps[wave][l16][ni * 16 + quad * 4] = *(const short4*)pb;
            }
            ssum += __shfl_xor(ssum, 16, 64);
            ssum += __shfl_xor(ssum, 32, 64);
            l_run[t] = l_run[t] * alpha + ssum;

            float ar[4];
#pragma unroll
            for (int r = 0; r < 4; ++r) ar[r] = __shfl(alpha, bsrc + r, 64);
#pragma unroll
            for (int db = 0; db < 8; ++db)
#pragma unroll
                for (int r = 0; r < 4; ++r) oacc[t][db][r] *= ar[r];

            asm volatile("s_waitcnt lgkmcnt(0)" ::: "memory");

#pragma unroll
            for (int kk = 0; kk < 2; ++kk) {
                bf16x8 ap = *(const bf16x8*)&Ps[wave][l16][kk * 32 + quad * 8];
                const int voff = ((kk * 4 + quad) ^ swz) * 8;
#pragma unroll
                for (int db = 0; db < 8; ++db) {
                    bf16x8 bv8 = *(const bf16x8*)(Vb + (db * 16 + l16) * 64 + voff);
                    oacc[t][db] = mfma_bf16(ap, bv8, oacc[t][db]);
                }
            }
        }

        __syncthreads();
    }

#pragma unroll
    for (int t = 0; t < 2; ++t) {
        const int q0t = t ? q0A : q0B;
        const float linv = 1.0f / l_run[t];
        float ir[4];
#pragma unroll
        for (int r = 0; r < 4; ++r) ir[r] = __shfl(linv, bsrc + r, 64);
#pragma unroll
        for (int r = 0; r < 4; ++r) {
            const int qg = q0t + qw + quad * 4 + r;
#pragma unroll
            for (int db = 0; db < 8; ++db)
                Og[(size_t)qg * DQ + db * 16 + l16] = __float2bfloat16(oacc[t][db][r] * ir[r]);
        }
    }
}

extern "C" void kernel_launch(void* const* d_in, const int* in_sizes, int n_in,
                              void* d_out, int out_size, void* d_ws, size_t ws_size,
                              hipStream_t stream)
{
    const float* hs = (const float*)d_in[0];
    const float* Wq = (const float*)d_in[1];
    const float* bq = (const float*)d_in[2];
    const float* Wk = (const float*)d_in[3];
    const float* bk = (const float*)d_in[4];
    const float* Wv = (const float*)d_in[5];
    const float* bv = (const float*)d_in[6];
    const float* Wo = (const float*)d_in[7];
    const float* bo = (const float*)d_in[8];
    float* out = (float*)d_out;

    const int M  = 4096;         // B*T tokens
    const int D  = 4096;
    const int DK = 1024;         // G*d
    const size_t SZ_D  = (size_t)M * D;
    const size_t SZ_K  = (size_t)M * DK;

    bf16* hsb  = (bf16*)d_ws;            // [M][D]
    bf16* Wqb  = hsb  + SZ_D;            // [D][D]
    bf16* Wkb  = Wqb  + SZ_D;            // [DK][D]
    bf16* Wvb  = Wkb  + SZ_K;            // [DK][D]
    bf16* Wob  = Wvb  + SZ_K;            // [D][D]
    bf16* q_buf = Wob + SZ_D;            // [M][D]
    bf16* k_buf = q_buf + SZ_D;          // [M][DK]
    bf16* vt_buf = Wqb;                  // ALIAS: Wq consumed before KV-gemm writes vt
    bf16* o_buf  = hsb;                  // ALIAS: hs consumed before attn writes o

    const int CB = 256;
    cvt_f32_bf16<<<(int)(SZ_D / 4 + CB - 1) / CB, CB, 0, stream>>>(hs, hsb, (int)SZ_D);
    cvt_f32_bf16<<<(int)(SZ_D / 4 + CB - 1) / CB, CB, 0, stream>>>(Wq, Wqb, (int)SZ_D);
    cvt_f32_bf16<<<(int)(SZ_K / 4 + CB - 1) / CB, CB, 0, stream>>>(Wk, Wkb, (int)SZ_K);
    cvt_f32_bf16<<<(int)(SZ_K / 4 + CB - 1) / CB, CB, 0, stream>>>(Wv, Wvb, (int)SZ_K);
    cvt_f32_bf16<<<(int)(SZ_D / 4 + CB - 1) / CB, CB, 0, stream>>>(Wo, Wob, (int)SZ_D);

    const float scale = 0.08838834764831845f;  // 1/sqrt(128), folded into Q
    gemm256_bt_bias<0><<<dim3(M / 256, D / 256), dim3(512), 0, stream>>>(hsb, Wqb, bq, q_buf, M, D, D, scale);
    gemm_kv<<<dim3(M / 128, 16), dim3(256), 0, stream>>>(hsb, Wkb, Wvb, bk, bv, k_buf, vt_buf, M, D);
    attn_fwd<<<dim3(16, 64), dim3(256), 0, stream>>>(q_buf, k_buf, vt_buf, o_buf);
    gemm256_bt_bias<1><<<dim3(M / 256, D / 256), dim3(512), 0, stream>>>(o_buf, Wob, bo, out, M, D, D, 1.0f);
}